// Round 5
// baseline (220.555 us; speedup 1.0000x reference)
//
#include <hip/hip_runtime.h>
#include <hip/hip_cooperative_groups.h>

namespace cg = cooperative_groups;

#define H 512
#define W 512
#define NPIX (H * W)
#define BIG_I 1073741824   // 2^30
#define BIG_F 1.0e6f
#define INF30 1.0e30f

// ---- workspace layout ----
// [0, NPIX) int32       : labels
// [NPIX, 2*NPIX) float  : dist buffer (row-pass result)
// then (64B aligned): Scal, Af[8192], Ab[8192], Asoa[256]
struct Scal {
  float soa;
  unsigned int min_bits;
  float cluster;
  unsigned int done;
  int both;
  float r0, r1;
  int sl, p0;
};

// ================= union-find (min-index roots) =================
__device__ __forceinline__ int rep(int* lab, int v) {
  int cur = lab[v];
  if (cur == v) return v;
  int prev = v, next;
  while (cur > (next = lab[cur])) { lab[prev] = next; prev = cur; cur = next; }
  return cur;
}
__device__ __forceinline__ void unite(int* lab, int a, int b) {
  int ra = rep(lab, a), rb = rep(lab, b);
  while (ra != rb) {
    if (ra < rb) { int t = ra; ra = rb; rb = t; }
    int old = atomicCAS(&lab[ra], ra, rb);
    if (old == ra) break;
    ra = rep(lab, old);
    rb = rep(lab, rb);
  }
}
__device__ __forceinline__ int root_ro(const int* lab, int v) {
  int n;
  while ((n = lab[v]) != v) v = n;   // parents strictly decrease; safe vs concurrent flatten
  return v;
}

__global__ __launch_bounds__(256) void k_fused(
    const float* __restrict__ img, const int* __restrict__ pts,
    int* lab, float* dist, float* Af, float* Ab, float* Asoa,
    Scal* s, float* out) {
  cg::grid_group grid = cg::this_grid();
  __shared__ int sl[1024];
  __shared__ float red[4];
  const int t = threadIdx.x;
  const int b = blockIdx.x;

  // ================= P1: per-tile (32x32) LDS CCL + soa partial =================
  {
    const int tileX = (b & 15) * 32;
    const int tileY = (b >> 4) * 32;
    const int r = t >> 3, c0 = (t & 7) * 4;     // thread owns 4 px of tile-row r
    const float4 x4 = *(const float4*)(img + (tileY + r) * W + tileX + c0);
    float acc = 4.0f - (x4.x + x4.y + x4.z + x4.w);
    unsigned nib = (rintf(x4.x) > 0.5f ? 1u : 0u) | (rintf(x4.y) > 0.5f ? 2u : 0u)
                 | (rintf(x4.z) > 0.5f ? 4u : 0u) | (rintf(x4.w) > 0.5f ? 8u : 0u);
    unsigned m = nib << c0;                      // row mask via 8-lane OR (lanes 8r..8r+7)
    m |= __shfl_xor(m, 1, 64);
    m |= __shfl_xor(m, 2, 64);
    m |= __shfl_xor(m, 4, 64);
    #pragma unroll
    for (int k = 0; k < 4; ++k) {                // run-start labels: horiz unions for free
      int c = c0 + k, li = (r << 5) + c;
      if ((m >> c) & 1u) {
        unsigned z = ~m & ((1u << c) - 1u);
        int start = z ? (32 - __clz((int)z)) : 0;
        sl[li] = (r << 5) + start;
      } else sl[li] = -1;
    }
    __syncthreads();
    if (r > 0) {                                 // vertical + diagonal unions
      #pragma unroll
      for (int k = 0; k < 4; ++k) {
        int c = c0 + k, li = (r << 5) + c;
        if (sl[li] < 0) continue;
        int q = li - 32;
        if (c > 0  && sl[q - 1] >= 0) unite(sl, li, q - 1);
        if (          sl[q]     >= 0) unite(sl, li, q);
        if (c < 31 && sl[q + 1] >= 0) unite(sl, li, q + 1);
      }
    }
    __syncthreads();
    int o[4];
    #pragma unroll
    for (int k = 0; k < 4; ++k) {
      int li = (r << 5) + c0 + k;
      if (sl[li] < 0) o[k] = BIG_I;
      else { int rt = rep(sl, li); o[k] = (tileY + (rt >> 5)) * W + tileX + (rt & 31); }
    }
    *(int4*)(lab + (tileY + r) * W + tileX + c0) = make_int4(o[0], o[1], o[2], o[3]);
    for (int off = 32; off; off >>= 1) acc += __shfl_down(acc, off, 64);
    if ((t & 63) == 0) red[t >> 6] = acc;
    __syncthreads();
    if (t == 0) Asoa[b] = red[0] + red[1] + red[2] + red[3];
  }
  grid.sync();

  // ================= P2: border merge (boundary-crossing edges only) =================
  {
    int gid = b * 256 + t;
    if (gid < 7680) {                            // horizontal boundary rows i=32,64,...
      int bb = gid >> 9, j = gid & 511;
      int i = (bb + 1) * 32;
      int p = i * W + j, q = p - W;
      if (lab[p] != BIG_I) {
        if (j > 0   && lab[q - 1] != BIG_I) unite(lab, p, q - 1);
        if (           lab[q]     != BIG_I) unite(lab, p, q);
        if (j < 511 && lab[q + 1] != BIG_I) unite(lab, p, q + 1);
      }
    } else if (gid < 15360) {                    // vertical boundary cols j=32,64,...
      int t2 = gid - 7680;
      int bb = t2 >> 9, i = t2 & 511;
      int j = (bb + 1) * 32;
      int p = i * W + j;
      int lp = lab[p], ll = lab[p - 1];
      if (lp != BIG_I && ll != BIG_I) unite(lab, p, p - 1);
      if (i & 31) {                              // diagonals not covered by horiz pass
        if (lp != BIG_I && lab[p - W - 1] != BIG_I) unite(lab, p, p - W - 1);
        if (ll != BIG_I && lab[p - W]     != BIG_I) unite(lab, p - 1, p - W);
      }
    }
  }
  grid.sync();

  // ====== P3: flatten + row min-plus scan (wave/row); block 255: scalar init ======
  {
    int lane = t & 63;
    int wid = b * 4 + (t >> 6);
    if (b == 255 && t < 64) {                    // idle block: soa reduce + Scal init
      float a = Asoa[t] + Asoa[t + 64] + Asoa[t + 128] + Asoa[t + 192];
      for (int off = 32; off; off >>= 1) a += __shfl_down(a, off, 64);
      if (t == 0) {
        int p0 = pts[0] * W + pts[1], p1 = pts[2] * W + pts[3];
        int l0 = lab[p0], l1 = lab[p1];
        int both = (l0 != BIG_I) && (l1 != BIG_I);
        s->soa = a;
        s->both = both;
        s->sl = both ? root_ro(lab, l0) : -1;
        s->p0 = p0;
        s->r0 = img[p0];
        s->r1 = img[p1];
        s->min_bits = __float_as_uint(BIG_F);
        s->cluster = 0.0f;
        s->done = 0u;
      }
    }
    if (wid < 512) {
      int row = wid;
      int el = -1;
      if (lane == 0) {
        int p0 = pts[0] * W + pts[1], p1 = pts[2] * W + pts[3];
        int l0 = lab[p0], l1 = lab[p1];
        el = ((l0 != BIG_I) && (l1 != BIG_I)) ? root_ro(lab, l1) : -1;
      }
      el = __shfl(el, 0, 64);
      int4* lp = (int4*)(lab + row * W) + lane * 2;
      int4 a = lp[0], bq = lp[1];
      int v[8] = {a.x, a.y, a.z, a.w, bq.x, bq.y, bq.z, bq.w};
      #pragma unroll
      for (int k = 0; k < 8; ++k)
        if (v[k] != BIG_I) v[k] = root_ro(lab, v[k]);
      lp[0] = make_int4(v[0], v[1], v[2], v[3]);
      lp[1] = make_int4(v[4], v[5], v[6], v[7]);
      float d[8];
      #pragma unroll
      for (int k = 0; k < 8; ++k) d[k] = (v[k] == el) ? 0.0f : BIG_F;
      int j0 = lane * 8;
      float pf[8], sb[8];
      float m = INF30;
      #pragma unroll
      for (int k = 0; k < 8; ++k) { m = fminf(m, d[k] - (float)(j0 + k)); pf[k] = m; }
      float tf = m;
      m = INF30;
      #pragma unroll
      for (int k = 7; k >= 0; --k) { m = fminf(m, d[k] + (float)(j0 + k)); sb[k] = m; }
      float tb = m;
      float vv = tf;
      #pragma unroll
      for (int off = 1; off < 64; off <<= 1) {
        float u = __shfl_up(vv, off, 64);
        if (lane >= off) vv = fminf(vv, u);
      }
      float ef = __shfl_up(vv, 1, 64); if (lane == 0) ef = INF30;
      vv = tb;
      #pragma unroll
      for (int off = 1; off < 64; off <<= 1) {
        float u = __shfl_down(vv, off, 64);
        if (lane < 64 - off) vv = fminf(vv, u);
      }
      float eb = __shfl_down(vv, 1, 64); if (lane == 63) eb = INF30;
      float o[8];
      #pragma unroll
      for (int k = 0; k < 8; ++k) {
        float j = (float)(j0 + k);
        o[k] = fminf(j + fminf(ef, pf[k]), -j + fminf(eb, sb[k]));
      }
      float4* dp = (float4*)(dist + row * W) + lane * 2;
      dp[0] = make_float4(o[0], o[1], o[2], o[3]);
      dp[1] = make_float4(o[4], o[5], o[6], o[7]);
    }
  }
  grid.sync();

  // ================= P4: per-(32-row segment, column) aggregates =================
  {
    int gid = b * 256 + t;
    if (gid < 8192) {
      int sg = gid >> 9, j = gid & 511;
      int i0 = sg * 32;
      float fa = INF30, fb = INF30;
      #pragma unroll 4
      for (int il = 0; il < 32; ++il) {
        float v = dist[(i0 + il) * W + j];
        float fi = (float)(i0 + il);
        fa = fminf(fa, v - fi);
        fb = fminf(fb, v + fi);
      }
      Af[gid] = fa;
      Ab[gid] = fb;
    }
  }
  grid.sync();

  // ===== P5: column apply + fused masked reduce + finalize (blocks 0..31) =====
  if (b < 32) {
    __shared__ float smin[4], ssum[4];
    int gid = b * 256 + t;
    int sg = gid >> 9, j = gid & 511;
    float cf = INF30, cb = INF30;
    #pragma unroll
    for (int bb = 0; bb < 16; ++bb) {
      if (bb < sg) cf = fminf(cf, Af[bb * 512 + j]);
      if (bb > sg) cb = fminf(cb, Ab[bb * 512 + j]);
    }
    int i0 = sg * 32;
    int slv = s->sl;
    int p0 = s->p0;
    float rr[32], ff[32];
    float m = cf;
    #pragma unroll
    for (int il = 0; il < 32; ++il) {
      rr[il] = dist[(i0 + il) * W + j];
      float fi = (float)(i0 + il);
      m = fminf(m, rr[il] - fi);
      ff[il] = fi + m;
    }
    m = cb;
    float dv = BIG_F, cv = 0.0f;
    #pragma unroll
    for (int il = 31; il >= 0; --il) {           // final dist consumed in-register
      int pix = (i0 + il) * W + j;
      float fi = (float)(i0 + il);
      m = fminf(m, rr[il] + fi);
      float o = fminf(ff[il], m - fi);
      if (lab[pix] == slv) { dv = fminf(dv, o); cv += img[pix]; }
      if (pix == p0) dv = fminf(dv, o);          // dist[p0] term, mask-independent
    }
    for (int off = 32; off; off >>= 1) {
      dv = fminf(dv, __shfl_down(dv, off, 64));
      cv += __shfl_down(cv, off, 64);
    }
    if ((t & 63) == 0) { smin[t >> 6] = dv; ssum[t >> 6] = cv; }
    __syncthreads();
    if (t == 0) {
      float mm = fminf(fminf(smin[0], smin[1]), fminf(smin[2], smin[3]));
      float su = ssum[0] + ssum[1] + ssum[2] + ssum[3];
      atomicMin(&s->min_bits, __float_as_uint(mm));  // dist >= 0: uint order == float order
      atomicAdd(&s->cluster, su);
      __threadfence();
      unsigned old = atomicAdd(&s->done, 1u);
      if (old == 31u) {
        float fallback = (2.0f - (s->r0 + s->r1)) * 100.0f;
        out[0] = fallback;
        float min_d = __uint_as_float(atomicOr(&s->min_bits, 0u));
        float cl = atomicAdd(&s->cluster, 0.0f);
        float soa = s->soa;
        out[1] = s->both ? (min_d * soa * 10.0f * soa) : fallback;
        out[2] = s->both ? (cl * 90.0f) : fallback;
      }
    }
  }
}

extern "C" void kernel_launch(void* const* d_in, const int* in_sizes, int n_in,
                              void* d_out, int out_size, void* d_ws, size_t ws_size,
                              hipStream_t stream) {
  const float* img = (const float*)d_in[0] + 3 * NPIX;   // result_given[3,0]
  const int* pts = (const int*)d_in[1] + 3 * 4;          // points_given[3]
  float* out = (float*)d_out;

  int* lab = (int*)d_ws;
  float* dist = (float*)d_ws + NPIX;
  char* base = (char*)d_ws + (size_t)2 * NPIX * 4;
  Scal* s = (Scal*)base;
  float* Af = (float*)(base + 64);
  float* Ab = Af + 8192;
  float* Asoa = Ab + 8192;

  void* args[] = {(void*)&img, (void*)&pts, (void*)&lab, (void*)&dist,
                  (void*)&Af, (void*)&Ab, (void*)&Asoa, (void*)&s, (void*)&out};
  hipLaunchCooperativeKernel((const void*)k_fused, dim3(256), dim3(256),
                             args, 0, stream);
}

// Round 6
// 116.284 us; speedup vs baseline: 1.8967x; 1.8967x over previous
//
#include <hip/hip_runtime.h>

#define H 512
#define W 512
#define NPIX (H * W)
#define BIG_I 1073741824   // 2^30
#define BIG_F 1.0e6f
#define INF30 1.0e30f

// ---- workspace layout ----
// [0, NPIX) int32       : labels
// [NPIX, 2*NPIX) float  : dist buffer (row-pass result)
// then (64B aligned): Scal, Af[8192], Ab[8192], Asoa[256]
struct Scal {
  float soa;
  unsigned int min_bits;
  float cluster;
  unsigned int done;
  int both;
  float r0, r1;
  int sl, p0;
};

// ================= union-find (min-index roots) =================
__device__ __forceinline__ int rep(int* lab, int v) {
  int cur = lab[v];
  if (cur == v) return v;
  int prev = v, next;
  while (cur > (next = lab[cur])) { lab[prev] = next; prev = cur; cur = next; }
  return cur;
}
__device__ __forceinline__ void unite(int* lab, int a, int b) {
  int ra = rep(lab, a), rb = rep(lab, b);
  while (ra != rb) {
    if (ra < rb) { int t = ra; ra = rb; rb = t; }
    int old = atomicCAS(&lab[ra], ra, rb);
    if (old == ra) break;
    ra = rep(lab, old);
    rb = rep(lab, rb);
  }
}
__device__ __forceinline__ int root_ro(const int* lab, int v) {
  int n;
  while ((n = lab[v]) != v) v = n;   // parents strictly decrease; safe vs concurrent flatten
  return v;
}

// ---- 1: per-tile (32x32) LDS CCL + soa partial ----
__global__ __launch_bounds__(256) void k_local(const float* __restrict__ img,
                                               int* __restrict__ lab,
                                               float* __restrict__ Asoa) {
  __shared__ int sl[1024];
  __shared__ float red[4];
  const int t = threadIdx.x, b = blockIdx.x;
  const int tileX = (b & 15) * 32;
  const int tileY = (b >> 4) * 32;
  const int r = t >> 3, c0 = (t & 7) * 4;     // thread owns 4 px of tile-row r
  const float4 x4 = *(const float4*)(img + (tileY + r) * W + tileX + c0);
  float acc = 4.0f - (x4.x + x4.y + x4.z + x4.w);
  unsigned nib = (rintf(x4.x) > 0.5f ? 1u : 0u) | (rintf(x4.y) > 0.5f ? 2u : 0u)
               | (rintf(x4.z) > 0.5f ? 4u : 0u) | (rintf(x4.w) > 0.5f ? 8u : 0u);
  unsigned m = nib << c0;                      // row mask via 3-step OR over lanes 8r..8r+7
  m |= __shfl_xor(m, 1, 64);
  m |= __shfl_xor(m, 2, 64);
  m |= __shfl_xor(m, 4, 64);
  #pragma unroll
  for (int k = 0; k < 4; ++k) {                // run-start labels: horiz unions for free
    int c = c0 + k, li = (r << 5) + c;
    if ((m >> c) & 1u) {
      unsigned z = ~m & ((1u << c) - 1u);
      int start = z ? (32 - __clz((int)z)) : 0;
      sl[li] = (r << 5) + start;
    } else sl[li] = -1;
  }
  __syncthreads();
  if (r > 0) {                                 // vertical + diagonal unions
    #pragma unroll
    for (int k = 0; k < 4; ++k) {
      int c = c0 + k, li = (r << 5) + c;
      if (sl[li] < 0) continue;
      int q = li - 32;
      if (c > 0  && sl[q - 1] >= 0) unite(sl, li, q - 1);
      if (          sl[q]     >= 0) unite(sl, li, q);
      if (c < 31 && sl[q + 1] >= 0) unite(sl, li, q + 1);
    }
  }
  __syncthreads();
  int o[4];
  #pragma unroll
  for (int k = 0; k < 4; ++k) {
    int li = (r << 5) + c0 + k;
    if (sl[li] < 0) o[k] = BIG_I;
    else { int rt = rep(sl, li); o[k] = (tileY + (rt >> 5)) * W + tileX + (rt & 31); }
  }
  *(int4*)(lab + (tileY + r) * W + tileX + c0) = make_int4(o[0], o[1], o[2], o[3]);
  for (int off = 32; off; off >>= 1) acc += __shfl_down(acc, off, 64);
  if ((t & 63) == 0) red[t >> 6] = acc;
  __syncthreads();
  if (t == 0) Asoa[b] = red[0] + red[1] + red[2] + red[3];
}

// ---- 2: border merge (blocks 0..59) + soa reduce / Scal init (block 60) ----
__global__ void k_border(int* __restrict__ lab, const float* __restrict__ Asoa,
                         Scal* __restrict__ s) {
  int t = threadIdx.x;
  int gid = blockIdx.x * 256 + t;
  if (gid < 7680) {                            // horizontal boundary rows i=32,64,...
    int bb = gid >> 9, j = gid & 511;
    int i = (bb + 1) * 32;
    int p = i * W + j, q = p - W;
    if (lab[p] != BIG_I) {
      if (j > 0   && lab[q - 1] != BIG_I) unite(lab, p, q - 1);
      if (           lab[q]     != BIG_I) unite(lab, p, q);
      if (j < 511 && lab[q + 1] != BIG_I) unite(lab, p, q + 1);
    }
  } else if (gid < 15360) {                    // vertical boundary cols j=32,64,...
    int t2 = gid - 7680;
    int bb = t2 >> 9, i = t2 & 511;
    int j = (bb + 1) * 32;
    int p = i * W + j;
    int lp = lab[p], ll = lab[p - 1];
    if (lp != BIG_I && ll != BIG_I) unite(lab, p, p - 1);
    if (i & 31) {                              // diagonals not covered by horiz pass
      if (lp != BIG_I && lab[p - W - 1] != BIG_I) unite(lab, p, p - W - 1);
      if (ll != BIG_I && lab[p - W]     != BIG_I) unite(lab, p - 1, p - W);
    }
  } else if (t < 64) {                         // block 60: reduce soa partials + init
    float a = Asoa[t] + Asoa[t + 64] + Asoa[t + 128] + Asoa[t + 192];
    for (int off = 32; off; off >>= 1) a += __shfl_down(a, off, 64);
    if (t == 0) {
      s->soa = a;
      s->min_bits = __float_as_uint(BIG_F);
      s->cluster = 0.0f;
      s->done = 0u;
    }
  }
}

// ---- 3: flatten + row min-plus scan (wave per row) + point-scalar init ----
__global__ __launch_bounds__(256) void k_dt_rows(int* __restrict__ lab,
                                                 const float* __restrict__ img,
                                                 const int* __restrict__ pts,
                                                 Scal* __restrict__ s,
                                                 float* __restrict__ dist) {
  int lane = threadIdx.x & 63;
  int row = blockIdx.x * 4 + (threadIdx.x >> 6);
  int el = -1;
  if (lane == 0) {
    int p0 = pts[0] * W + pts[1], p1 = pts[2] * W + pts[3];
    int l0 = lab[p0], l1 = lab[p1];
    int both = (l0 != BIG_I) && (l1 != BIG_I);
    el = both ? root_ro(lab, l1) : -1;
    if (blockIdx.x == 0 && threadIdx.x == 0) {
      s->both = both;
      s->sl = both ? root_ro(lab, l0) : -1;
      s->p0 = p0;
      s->r0 = img[p0];
      s->r1 = img[p1];
    }
  }
  el = __shfl(el, 0, 64);
  int4* lp = (int4*)(lab + row * W) + lane * 2;
  int4 a = lp[0], bq = lp[1];
  int v[8] = {a.x, a.y, a.z, a.w, bq.x, bq.y, bq.z, bq.w};
  #pragma unroll
  for (int k = 0; k < 8; ++k)
    if (v[k] != BIG_I) v[k] = root_ro(lab, v[k]);   // flatten (read-only walk)
  lp[0] = make_int4(v[0], v[1], v[2], v[3]);        // write back final labels
  lp[1] = make_int4(v[4], v[5], v[6], v[7]);
  float d[8];
  #pragma unroll
  for (int k = 0; k < 8; ++k) d[k] = (v[k] == el) ? 0.0f : BIG_F;
  int j0 = lane * 8;
  float pf[8], sb[8];
  float m = INF30;
  #pragma unroll
  for (int k = 0; k < 8; ++k) { m = fminf(m, d[k] - (float)(j0 + k)); pf[k] = m; }
  float tf = m;
  m = INF30;
  #pragma unroll
  for (int k = 7; k >= 0; --k) { m = fminf(m, d[k] + (float)(j0 + k)); sb[k] = m; }
  float tb = m;
  float vv = tf;
  #pragma unroll
  for (int off = 1; off < 64; off <<= 1) {
    float u = __shfl_up(vv, off, 64);
    if (lane >= off) vv = fminf(vv, u);
  }
  float ef = __shfl_up(vv, 1, 64); if (lane == 0) ef = INF30;
  vv = tb;
  #pragma unroll
  for (int off = 1; off < 64; off <<= 1) {
    float u = __shfl_down(vv, off, 64);
    if (lane < 64 - off) vv = fminf(vv, u);
  }
  float eb = __shfl_down(vv, 1, 64); if (lane == 63) eb = INF30;
  float o[8];
  #pragma unroll
  for (int k = 0; k < 8; ++k) {
    float j = (float)(j0 + k);
    o[k] = fminf(j + fminf(ef, pf[k]), -j + fminf(eb, sb[k]));
  }
  float4* dp = (float4*)(dist + row * W) + lane * 2;
  dp[0] = make_float4(o[0], o[1], o[2], o[3]);
  dp[1] = make_float4(o[4], o[5], o[6], o[7]);
}

// ---- 4: per-(32-row segment, column) aggregates ----
__global__ void k_dt_colA(const float* __restrict__ dist,
                          float* __restrict__ Af, float* __restrict__ Ab) {
  int gid = blockIdx.x * blockDim.x + threadIdx.x;   // 0..8191
  int sg = gid >> 9, j = gid & 511;
  int i0 = sg * 32;
  float fa = INF30, fb = INF30;
  #pragma unroll 4
  for (int il = 0; il < 32; ++il) {
    float v = dist[(i0 + il) * W + j];
    float fi = (float)(i0 + il);
    fa = fminf(fa, v - fi);
    fb = fminf(fb, v + fi);
  }
  Af[gid] = fa;
  Ab[gid] = fb;
}

// ---- 5: column apply + fused masked reduce + finalize ----
__global__ __launch_bounds__(256) void k_dt_colfin(
    const float* __restrict__ dist, const float* __restrict__ Af,
    const float* __restrict__ Ab, const int* __restrict__ lab,
    const float* __restrict__ img, Scal* __restrict__ s,
    float* __restrict__ out) {
  __shared__ float smin[4], ssum[4];
  int t = threadIdx.x;
  int gid = blockIdx.x * 256 + t;
  int sg = gid >> 9, j = gid & 511;
  float cf = INF30, cb = INF30;
  #pragma unroll
  for (int bb = 0; bb < 16; ++bb) {
    if (bb < sg) cf = fminf(cf, Af[bb * 512 + j]);
    if (bb > sg) cb = fminf(cb, Ab[bb * 512 + j]);
  }
  int i0 = sg * 32;
  int slv = s->sl;
  int p0 = s->p0;
  float rr[32], ff[32];
  float m = cf;
  #pragma unroll
  for (int il = 0; il < 32; ++il) {
    rr[il] = dist[(i0 + il) * W + j];
    float fi = (float)(i0 + il);
    m = fminf(m, rr[il] - fi);
    ff[il] = fi + m;
  }
  m = cb;
  float dv = BIG_F, cv = 0.0f;
  #pragma unroll
  for (int il = 31; il >= 0; --il) {           // final dist consumed in-register
    int pix = (i0 + il) * W + j;
    float fi = (float)(i0 + il);
    m = fminf(m, rr[il] + fi);
    float o = fminf(ff[il], m - fi);
    if (lab[pix] == slv) { dv = fminf(dv, o); cv += img[pix]; }
    if (pix == p0) dv = fminf(dv, o);          // dist[p0] term, mask-independent
  }
  for (int off = 32; off; off >>= 1) {
    dv = fminf(dv, __shfl_down(dv, off, 64));
    cv += __shfl_down(cv, off, 64);
  }
  if ((t & 63) == 0) { smin[t >> 6] = dv; ssum[t >> 6] = cv; }
  __syncthreads();
  if (t == 0) {
    float mm = fminf(fminf(smin[0], smin[1]), fminf(smin[2], smin[3]));
    float su = ssum[0] + ssum[1] + ssum[2] + ssum[3];
    atomicMin(&s->min_bits, __float_as_uint(mm));  // dist >= 0: uint order == float order
    atomicAdd(&s->cluster, su);
    __threadfence();
    unsigned old = atomicAdd(&s->done, 1u);
    if (old == gridDim.x - 1) {
      float fallback = (2.0f - (s->r0 + s->r1)) * 100.0f;
      out[0] = fallback;
      float min_d = __uint_as_float(atomicOr(&s->min_bits, 0u));
      float cl = atomicAdd(&s->cluster, 0.0f);
      float soa = s->soa;
      out[1] = s->both ? (min_d * soa * 10.0f * soa) : fallback;
      out[2] = s->both ? (cl * 90.0f) : fallback;
    }
  }
}

extern "C" void kernel_launch(void* const* d_in, const int* in_sizes, int n_in,
                              void* d_out, int out_size, void* d_ws, size_t ws_size,
                              hipStream_t stream) {
  const float* img = (const float*)d_in[0] + 3 * NPIX;   // result_given[3,0]
  const int* pts = (const int*)d_in[1] + 3 * 4;          // points_given[3]
  float* out = (float*)d_out;

  int* lab = (int*)d_ws;
  float* dist = (float*)d_ws + NPIX;
  char* base = (char*)d_ws + (size_t)2 * NPIX * 4;
  Scal* s = (Scal*)base;
  float* Af = (float*)(base + 64);
  float* Ab = Af + 8192;
  float* Asoa = Ab + 8192;

  k_local<<<256, 256, 0, stream>>>(img, lab, Asoa);
  k_border<<<61, 256, 0, stream>>>(lab, Asoa, s);
  k_dt_rows<<<H / 4, 256, 0, stream>>>(lab, img, pts, s, dist);
  k_dt_colA<<<32, 256, 0, stream>>>(dist, Af, Ab);
  k_dt_colfin<<<32, 256, 0, stream>>>(dist, Af, Ab, lab, img, s, out);
}

// Round 7
// 104.830 us; speedup vs baseline: 2.1039x; 1.1093x over previous
//
#include <hip/hip_runtime.h>

#define H 512
#define W 512
#define NPIX (H * W)
#define BIG_I 1073741824   // 2^30
#define BIG_F 1.0e6f
#define INF30 1.0e30f

// ---- workspace layout ----
// [0, NPIX) int32       : labels
// [NPIX, 2*NPIX) float  : dist buffer (row-pass result)
// then (64B aligned): Scal, Asoa[256]
struct Scal {
  float soa;
  unsigned int min_bits;
  float cluster;
  unsigned int done;
  int both;
  float r0, r1;
  int sl, p0;
};

// ================= union-find (min-index roots) =================
__device__ __forceinline__ int rep(int* lab, int v) {
  int cur = lab[v];
  if (cur == v) return v;
  int prev = v, next;
  while (cur > (next = lab[cur])) { lab[prev] = next; prev = cur; cur = next; }
  return cur;
}
__device__ __forceinline__ void unite(int* lab, int a, int b) {
  int ra = rep(lab, a), rb = rep(lab, b);
  while (ra != rb) {
    if (ra < rb) { int t = ra; ra = rb; rb = t; }
    int old = atomicCAS(&lab[ra], ra, rb);
    if (old == ra) break;
    ra = rep(lab, old);
    rb = rep(lab, rb);
  }
}
__device__ __forceinline__ int root_ro(const int* lab, int v) {
  int n;
  while ((n = lab[v]) != v) v = n;   // parents strictly decrease
  return v;
}
// run start column of bit c in mask (bit c must be set)
__device__ __forceinline__ int runstart(unsigned m, int c) {
  unsigned z = ~m & ((1u << c) - 1u);
  return z ? (32 - __clz((int)z)) : 0;
}

// ---- 1: per-tile (32x32) LDS CCL (run-based, pruned unions) + soa partial ----
__global__ __launch_bounds__(256) void k_local(const float* __restrict__ img,
                                               int* __restrict__ lab,
                                               float* __restrict__ Asoa) {
  __shared__ int sl[1024];           // only run-start slots are ever used
  __shared__ unsigned rmask[32];
  __shared__ float red[4];
  const int t = threadIdx.x, b = blockIdx.x;
  const int tileX = (b & 15) * 32;
  const int tileY = (b >> 4) * 32;
  const int r = t >> 3, c0 = (t & 7) * 4;     // thread owns 4 px of tile-row r
  const float4 x4 = *(const float4*)(img + (tileY + r) * W + tileX + c0);
  float acc = 4.0f - (x4.x + x4.y + x4.z + x4.w);
  unsigned nib = (rintf(x4.x) > 0.5f ? 1u : 0u) | (rintf(x4.y) > 0.5f ? 2u : 0u)
               | (rintf(x4.z) > 0.5f ? 4u : 0u) | (rintf(x4.w) > 0.5f ? 8u : 0u);
  unsigned m = nib << c0;                      // full row mask via OR over lanes 8r..8r+7
  m |= __shfl_xor(m, 1, 64);
  m |= __shfl_xor(m, 2, 64);
  m |= __shfl_xor(m, 4, 64);
  if ((t & 7) == 0) rmask[r] = m;
  unsigned startM = m & ~(m << 1);
  #pragma unroll
  for (int k = 0; k < 4; ++k) {                // init union-find at run starts only
    int c = c0 + k;
    if ((startM >> c) & 1u) sl[(r << 5) + c] = (r << 5) + c;
  }
  __syncthreads();
  if (r > 0) {
    unsigned ma = rmask[r - 1];
    // one unite per adjacent (run, above-run) pair:
    unsigned upM = m & ma & (~(m << 1) | ~(ma << 1));
    unsigned dL  = startM & (ma << 1) & ~ma;               // c==runstart, above[c-1] fg, above[c] bg
    unsigned dR  = (m & ~(m >> 1)) & (ma >> 1) & ~ma;      // c==runend,  above[c+1] fg, above[c] bg
    #pragma unroll
    for (int k = 0; k < 4; ++k) {
      int c = c0 + k;
      int myS = (r << 5) + runstart(m, c);
      if ((upM >> c) & 1u) unite(sl, myS, ((r - 1) << 5) + runstart(ma, c));
      if ((dL  >> c) & 1u) unite(sl, myS, ((r - 1) << 5) + runstart(ma, c - 1));
      if ((dR  >> c) & 1u) unite(sl, myS, ((r - 1) << 5) + c + 1);
    }
  }
  __syncthreads();
  int o[4];
  #pragma unroll
  for (int k = 0; k < 4; ++k) {
    int c = c0 + k;
    if ((m >> c) & 1u) {
      int rt = rep(sl, (r << 5) + runstart(m, c));
      o[k] = (tileY + (rt >> 5)) * W + tileX + (rt & 31);
    } else o[k] = BIG_I;
  }
  *(int4*)(lab + (tileY + r) * W + tileX + c0) = make_int4(o[0], o[1], o[2], o[3]);
  for (int off = 32; off; off >>= 1) acc += __shfl_down(acc, off, 64);
  if ((t & 63) == 0) red[t >> 6] = acc;
  __syncthreads();
  if (t == 0) Asoa[b] = red[0] + red[1] + red[2] + red[3];
}

// ---- 2: border merge (blocks 0..59) + soa reduce / Scal init (block 60) ----
__global__ void k_border(int* __restrict__ lab, const float* __restrict__ Asoa,
                         Scal* __restrict__ s) {
  int t = threadIdx.x;
  int gid = blockIdx.x * 256 + t;
  if (gid < 7680) {                            // horizontal boundary rows i=32,64,...
    int bb = gid >> 9, j = gid & 511;
    int i = (bb + 1) * 32;
    int p = i * W + j, q = p - W;
    if (lab[p] != BIG_I) {
      if (j > 0   && lab[q - 1] != BIG_I) unite(lab, p, q - 1);
      if (           lab[q]     != BIG_I) unite(lab, p, q);
      if (j < 511 && lab[q + 1] != BIG_I) unite(lab, p, q + 1);
    }
  } else if (gid < 15360) {                    // vertical boundary cols j=32,64,...
    int t2 = gid - 7680;
    int bb = t2 >> 9, i = t2 & 511;
    int j = (bb + 1) * 32;
    int p = i * W + j;
    int lp = lab[p], ll = lab[p - 1];
    if (lp != BIG_I && ll != BIG_I) unite(lab, p, p - 1);
    if (i & 31) {                              // diagonals not covered by horiz pass
      if (lp != BIG_I && lab[p - W - 1] != BIG_I) unite(lab, p, p - W - 1);
      if (ll != BIG_I && lab[p - W]     != BIG_I) unite(lab, p - 1, p - W);
    }
  } else if (t < 64) {                         // block 60: reduce soa partials + init
    float a = Asoa[t] + Asoa[t + 64] + Asoa[t + 128] + Asoa[t + 192];
    for (int off = 32; off; off >>= 1) a += __shfl_down(a, off, 64);
    if (t == 0) {
      s->soa = a;
      s->min_bits = __float_as_uint(BIG_F);
      s->cluster = 0.0f;
      s->done = 0u;
    }
  }
}

// ---- 3: flatten + row min-plus scan (wave per row) + point-scalar init ----
__global__ __launch_bounds__(256) void k_dt_rows(int* __restrict__ lab,
                                                 const float* __restrict__ img,
                                                 const int* __restrict__ pts,
                                                 Scal* __restrict__ s,
                                                 float* __restrict__ dist) {
  int lane = threadIdx.x & 63;
  int row = blockIdx.x * 4 + (threadIdx.x >> 6);
  int el = -1;
  if (lane == 0) {
    int p0 = pts[0] * W + pts[1], p1 = pts[2] * W + pts[3];
    int l0 = lab[p0], l1 = lab[p1];
    int both = (l0 != BIG_I) && (l1 != BIG_I);
    el = both ? root_ro(lab, l1) : -1;
    if (blockIdx.x == 0 && threadIdx.x == 0) {
      s->both = both;
      s->sl = both ? root_ro(lab, l0) : -1;
      s->p0 = p0;
      s->r0 = img[p0];
      s->r1 = img[p1];
    }
  }
  el = __shfl(el, 0, 64);
  int4* lp = (int4*)(lab + row * W) + lane * 2;
  int4 a = lp[0], bq = lp[1];
  int v[8] = {a.x, a.y, a.z, a.w, bq.x, bq.y, bq.z, bq.w};
  #pragma unroll
  for (int k = 0; k < 8; ++k)
    if (v[k] != BIG_I) v[k] = root_ro(lab, v[k]);   // flatten (read-only walk)
  lp[0] = make_int4(v[0], v[1], v[2], v[3]);        // write back final labels
  lp[1] = make_int4(v[4], v[5], v[6], v[7]);
  float d[8];
  #pragma unroll
  for (int k = 0; k < 8; ++k) d[k] = (v[k] == el) ? 0.0f : BIG_F;
  int j0 = lane * 8;
  float pf[8], sb[8];
  float m = INF30;
  #pragma unroll
  for (int k = 0; k < 8; ++k) { m = fminf(m, d[k] - (float)(j0 + k)); pf[k] = m; }
  float tf = m;
  m = INF30;
  #pragma unroll
  for (int k = 7; k >= 0; --k) { m = fminf(m, d[k] + (float)(j0 + k)); sb[k] = m; }
  float tb = m;
  float vv = tf;
  #pragma unroll
  for (int off = 1; off < 64; off <<= 1) {
    float u = __shfl_up(vv, off, 64);
    if (lane >= off) vv = fminf(vv, u);
  }
  float ef = __shfl_up(vv, 1, 64); if (lane == 0) ef = INF30;
  vv = tb;
  #pragma unroll
  for (int off = 1; off < 64; off <<= 1) {
    float u = __shfl_down(vv, off, 64);
    if (lane < 64 - off) vv = fminf(vv, u);
  }
  float eb = __shfl_down(vv, 1, 64); if (lane == 63) eb = INF30;
  float o[8];
  #pragma unroll
  for (int k = 0; k < 8; ++k) {
    float j = (float)(j0 + k);
    o[k] = fminf(j + fminf(ef, pf[k]), -j + fminf(eb, sb[k]));
  }
  float4* dp = (float4*)(dist + row * W) + lane * 2;
  dp[0] = make_float4(o[0], o[1], o[2], o[3]);
  dp[1] = make_float4(o[4], o[5], o[6], o[7]);
}

// ---- 4: column DT (two-level scan via LDS) + masked reduce + finalize ----
// 16 blocks x 512 threads; block owns 32 columns, thread = (segment sg, col c).
__global__ __launch_bounds__(512) void k_dt_colfin(
    const float* __restrict__ dist, const int* __restrict__ lab,
    const float* __restrict__ img, Scal* __restrict__ s,
    float* __restrict__ out) {
  __shared__ float laf[16][32], lbb[16][32];
  __shared__ float smin[8], ssum[8];
  int t = threadIdx.x;
  int sg = t >> 5, c = t & 31;
  int j = blockIdx.x * 32 + c;
  int i0 = sg * 32;
  float rr[32];
  float fa = INF30, fb = INF30;
  #pragma unroll
  for (int il = 0; il < 32; ++il) {
    rr[il] = dist[(i0 + il) * W + j];
    float fi = (float)(i0 + il);
    fa = fminf(fa, rr[il] - fi);
    fb = fminf(fb, rr[il] + fi);
  }
  laf[sg][c] = fa;
  lbb[sg][c] = fb;
  __syncthreads();
  float cf = INF30, cb = INF30;
  #pragma unroll
  for (int bb = 0; bb < 16; ++bb) {
    if (bb < sg) cf = fminf(cf, laf[bb][c]);
    if (bb > sg) cb = fminf(cb, lbb[bb][c]);
  }
  int slv = s->sl;
  int p0 = s->p0;
  float ff[32];
  float m = cf;
  #pragma unroll
  for (int il = 0; il < 32; ++il) {
    float fi = (float)(i0 + il);
    m = fminf(m, rr[il] - fi);
    ff[il] = fi + m;
  }
  m = cb;
  float dv = BIG_F, cv = 0.0f;
  #pragma unroll
  for (int il = 31; il >= 0; --il) {           // final dist consumed in-register
    int pix = (i0 + il) * W + j;
    float fi = (float)(i0 + il);
    m = fminf(m, rr[il] + fi);
    float o = fminf(ff[il], m - fi);
    if (lab[pix] == slv) { dv = fminf(dv, o); cv += img[pix]; }
    if (pix == p0) dv = fminf(dv, o);          // dist[p0] term, mask-independent
  }
  for (int off = 32; off; off >>= 1) {
    dv = fminf(dv, __shfl_down(dv, off, 64));
    cv += __shfl_down(cv, off, 64);
  }
  if ((t & 63) == 0) { smin[t >> 6] = dv; ssum[t >> 6] = cv; }
  __syncthreads();
  if (t == 0) {
    float mm = INF30, su = 0.0f;
    #pragma unroll
    for (int w = 0; w < 8; ++w) { mm = fminf(mm, smin[w]); su += ssum[w]; }
    atomicMin(&s->min_bits, __float_as_uint(mm));  // dist >= 0: uint order == float order
    atomicAdd(&s->cluster, su);
    __threadfence();
    unsigned old = atomicAdd(&s->done, 1u);
    if (old == gridDim.x - 1) {
      float fallback = (2.0f - (s->r0 + s->r1)) * 100.0f;
      out[0] = fallback;
      float min_d = __uint_as_float(atomicOr(&s->min_bits, 0u));
      float cl = atomicAdd(&s->cluster, 0.0f);
      float soa = s->soa;
      out[1] = s->both ? (min_d * soa * 10.0f * soa) : fallback;
      out[2] = s->both ? (cl * 90.0f) : fallback;
    }
  }
}

extern "C" void kernel_launch(void* const* d_in, const int* in_sizes, int n_in,
                              void* d_out, int out_size, void* d_ws, size_t ws_size,
                              hipStream_t stream) {
  const float* img = (const float*)d_in[0] + 3 * NPIX;   // result_given[3,0]
  const int* pts = (const int*)d_in[1] + 3 * 4;          // points_given[3]
  float* out = (float*)d_out;

  int* lab = (int*)d_ws;
  float* dist = (float*)d_ws + NPIX;
  char* base = (char*)d_ws + (size_t)2 * NPIX * 4;
  Scal* s = (Scal*)base;
  float* Asoa = (float*)(base + 64);

  k_local<<<256, 256, 0, stream>>>(img, lab, Asoa);
  k_border<<<61, 256, 0, stream>>>(lab, Asoa, s);
  k_dt_rows<<<H / 4, 256, 0, stream>>>(lab, img, pts, s, dist);
  k_dt_colfin<<<16, 512, 0, stream>>>(dist, lab, img, s, out);
}

// Round 8
// 101.962 us; speedup vs baseline: 2.1631x; 1.0281x over previous
//
#include <hip/hip_runtime.h>

#define H 512
#define W 512
#define NPIX (H * W)
#define BIG_I 1073741824   // 2^30
#define BIG_F 1.0e6f
#define INF30 1.0e30f

// ---- workspace layout ----
// [0, NPIX) int32       : lab  (union-find forest; never finalized in place)
// [NPIX, 2*NPIX) float  : dist (row-pass result)
// then (64B aligned): Scal, Asoa[256], then lab2[NPIX] (final labels)
struct Scal {
  float soa;
  unsigned int min_bits;
  float cluster;
  unsigned int done;
  int both;
  float r0, r1;
  int sl, p0;
};

// ================= union-find (min-index roots) =================
__device__ __forceinline__ int rep(int* lab, int v) {
  int cur = lab[v];
  if (cur == v) return v;
  int prev = v, next;
  while (cur > (next = lab[cur])) { lab[prev] = next; prev = cur; cur = next; }
  return cur;
}
__device__ __forceinline__ void unite(int* lab, int a, int b) {
  int ra = rep(lab, a), rb = rep(lab, b);
  while (ra != rb) {
    if (ra < rb) { int t = ra; ra = rb; rb = t; }
    int old = atomicCAS(&lab[ra], ra, rb);
    if (old == ra) break;
    ra = rep(lab, old);
    rb = rep(lab, rb);
  }
}
__device__ __forceinline__ int root_ro(const int* lab, int v) {
  int n;
  while ((n = lab[v]) != v) v = n;
  return v;
}
// path-halving walk: writes only ancestors (monotone), safe concurrent w/ readers
__device__ __forceinline__ int root_ph(int* lab, int v) {
  int p = lab[v];
  if (p == v) return v;
  int gp = lab[p];
  while (p != gp) {
    lab[v] = gp;     // halve: benign race, gp is an ancestor of v
    v = p; p = gp; gp = lab[p];
  }
  return p;
}
// run start column of bit c in mask (bit c must be set)
__device__ __forceinline__ int runstart(unsigned m, int c) {
  unsigned z = ~m & ((1u << c) - 1u);
  return z ? (32 - __clz((int)z)) : 0;
}

// ---- 1: per-tile (32x32) LDS CCL (run-based, pruned unions) + soa partial ----
__global__ __launch_bounds__(256) void k_local(const float* __restrict__ img,
                                               int* __restrict__ lab,
                                               float* __restrict__ Asoa) {
  __shared__ int sl[1024];           // only run-start slots are ever used
  __shared__ unsigned rmask[32];
  __shared__ float red[4];
  const int t = threadIdx.x, b = blockIdx.x;
  const int tileX = (b & 15) * 32;
  const int tileY = (b >> 4) * 32;
  const int r = t >> 3, c0 = (t & 7) * 4;     // thread owns 4 px of tile-row r
  const float4 x4 = *(const float4*)(img + (tileY + r) * W + tileX + c0);
  float acc = 4.0f - (x4.x + x4.y + x4.z + x4.w);
  unsigned nib = (rintf(x4.x) > 0.5f ? 1u : 0u) | (rintf(x4.y) > 0.5f ? 2u : 0u)
               | (rintf(x4.z) > 0.5f ? 4u : 0u) | (rintf(x4.w) > 0.5f ? 8u : 0u);
  unsigned m = nib << c0;                      // full row mask via OR over lanes 8r..8r+7
  m |= __shfl_xor(m, 1, 64);
  m |= __shfl_xor(m, 2, 64);
  m |= __shfl_xor(m, 4, 64);
  if ((t & 7) == 0) rmask[r] = m;
  unsigned startM = m & ~(m << 1);
  #pragma unroll
  for (int k = 0; k < 4; ++k) {                // init union-find at run starts only
    int c = c0 + k;
    if ((startM >> c) & 1u) sl[(r << 5) + c] = (r << 5) + c;
  }
  __syncthreads();
  if (r > 0) {
    unsigned ma = rmask[r - 1];
    unsigned upM = m & ma & (~(m << 1) | ~(ma << 1));      // one unite per (run, above-run) pair
    unsigned dL  = startM & (ma << 1) & ~ma;
    unsigned dR  = (m & ~(m >> 1)) & (ma >> 1) & ~ma;
    #pragma unroll
    for (int k = 0; k < 4; ++k) {
      int c = c0 + k;
      int myS = (r << 5) + runstart(m, c);
      if ((upM >> c) & 1u) unite(sl, myS, ((r - 1) << 5) + runstart(ma, c));
      if ((dL  >> c) & 1u) unite(sl, myS, ((r - 1) << 5) + runstart(ma, c - 1));
      if ((dR  >> c) & 1u) unite(sl, myS, ((r - 1) << 5) + c + 1);
    }
  }
  __syncthreads();
  int o[4];
  #pragma unroll
  for (int k = 0; k < 4; ++k) {
    int c = c0 + k;
    if ((m >> c) & 1u) {
      int rt = rep(sl, (r << 5) + runstart(m, c));
      o[k] = (tileY + (rt >> 5)) * W + tileX + (rt & 31);
    } else o[k] = BIG_I;
  }
  *(int4*)(lab + (tileY + r) * W + tileX + c0) = make_int4(o[0], o[1], o[2], o[3]);
  for (int off = 32; off; off >>= 1) acc += __shfl_down(acc, off, 64);
  if ((t & 63) == 0) red[t >> 6] = acc;
  __syncthreads();
  if (t == 0) Asoa[b] = red[0] + red[1] + red[2] + red[3];
}

// ---- 2: border merge (blocks 0..59) + soa reduce / Scal init (block 60) ----
__global__ void k_border(int* __restrict__ lab, const float* __restrict__ Asoa,
                         Scal* __restrict__ s) {
  int t = threadIdx.x;
  int gid = blockIdx.x * 256 + t;
  if (gid < 7680) {                            // horizontal boundary rows i=32,64,...
    int bb = gid >> 9, j = gid & 511;
    int i = (bb + 1) * 32;
    int p = i * W + j, q = p - W;
    if (lab[p] != BIG_I) {
      if (j > 0   && lab[q - 1] != BIG_I) unite(lab, p, q - 1);
      if (           lab[q]     != BIG_I) unite(lab, p, q);
      if (j < 511 && lab[q + 1] != BIG_I) unite(lab, p, q + 1);
    }
  } else if (gid < 15360) {                    // vertical boundary cols j=32,64,...
    int t2 = gid - 7680;
    int bb = t2 >> 9, i = t2 & 511;
    int j = (bb + 1) * 32;
    int p = i * W + j;
    int lp = lab[p], ll = lab[p - 1];
    if (lp != BIG_I && ll != BIG_I) unite(lab, p, p - 1);
    if (i & 31) {                              // diagonals not covered by horiz pass
      if (lp != BIG_I && lab[p - W - 1] != BIG_I) unite(lab, p, p - W - 1);
      if (ll != BIG_I && lab[p - W]     != BIG_I) unite(lab, p - 1, p - W);
    }
  } else if (t < 64) {                         // block 60: reduce soa partials + init
    float a = Asoa[t] + Asoa[t + 64] + Asoa[t + 128] + Asoa[t + 192];
    for (int off = 32; off; off >>= 1) a += __shfl_down(a, off, 64);
    if (t == 0) {
      s->soa = a;
      s->min_bits = __float_as_uint(BIG_F);
      s->cluster = 0.0f;
      s->done = 0u;
    }
  }
}

// ---- 3: flatten (memo + path-halving) + row min-plus scan + scalar init ----
__global__ __launch_bounds__(256) void k_dt_rows(int* __restrict__ lab,
                                                 int* __restrict__ lab2,
                                                 const float* __restrict__ img,
                                                 const int* __restrict__ pts,
                                                 Scal* __restrict__ s,
                                                 float* __restrict__ dist) {
  int lane = threadIdx.x & 63;
  int row = blockIdx.x * 4 + (threadIdx.x >> 6);
  int el = -1;
  if (lane == 0) {
    int p0 = pts[0] * W + pts[1], p1 = pts[2] * W + pts[3];
    int l0 = lab[p0], l1 = lab[p1];
    int both = (l0 != BIG_I) && (l1 != BIG_I);
    el = both ? root_ph(lab, l1) : -1;
    if (blockIdx.x == 0 && threadIdx.x == 0) {
      s->both = both;
      s->sl = both ? root_ph(lab, l0) : -1;
      s->p0 = p0;
      s->r0 = img[p0];
      s->r1 = img[p1];
    }
  }
  el = __shfl(el, 0, 64);
  const int4* lp = (const int4*)(lab + row * W) + lane * 2;
  int4 a = lp[0], bq = lp[1];
  int v[8] = {a.x, a.y, a.z, a.w, bq.x, bq.y, bq.z, bq.w};
  int psrc = -1, proot = -1;
  #pragma unroll
  for (int k = 0; k < 8; ++k) {                // flatten w/ memo + halving
    if (v[k] == BIG_I) continue;
    if (v[k] == psrc) { v[k] = proot; continue; }
    psrc = v[k];
    proot = root_ph(lab, v[k]);
    v[k] = proot;
  }
  int4* l2 = (int4*)(lab2 + row * W) + lane * 2;   // final labels to clean array
  l2[0] = make_int4(v[0], v[1], v[2], v[3]);
  l2[1] = make_int4(v[4], v[5], v[6], v[7]);
  float d[8];
  #pragma unroll
  for (int k = 0; k < 8; ++k) d[k] = (v[k] == el) ? 0.0f : BIG_F;
  int j0 = lane * 8;
  float pf[8], sb[8];
  float m = INF30;
  #pragma unroll
  for (int k = 0; k < 8; ++k) { m = fminf(m, d[k] - (float)(j0 + k)); pf[k] = m; }
  float tf = m;
  m = INF30;
  #pragma unroll
  for (int k = 7; k >= 0; --k) { m = fminf(m, d[k] + (float)(j0 + k)); sb[k] = m; }
  float tb = m;
  float vv = tf;
  #pragma unroll
  for (int off = 1; off < 64; off <<= 1) {
    float u = __shfl_up(vv, off, 64);
    if (lane >= off) vv = fminf(vv, u);
  }
  float ef = __shfl_up(vv, 1, 64); if (lane == 0) ef = INF30;
  vv = tb;
  #pragma unroll
  for (int off = 1; off < 64; off <<= 1) {
    float u = __shfl_down(vv, off, 64);
    if (lane < 64 - off) vv = fminf(vv, u);
  }
  float eb = __shfl_down(vv, 1, 64); if (lane == 63) eb = INF30;
  float o[8];
  #pragma unroll
  for (int k = 0; k < 8; ++k) {
    float j = (float)(j0 + k);
    o[k] = fminf(j + fminf(ef, pf[k]), -j + fminf(eb, sb[k]));
  }
  float4* dp = (float4*)(dist + row * W) + lane * 2;
  dp[0] = make_float4(o[0], o[1], o[2], o[3]);
  dp[1] = make_float4(o[4], o[5], o[6], o[7]);
}

// ---- 4: column DT (two-level scan via LDS) + masked reduce + finalize ----
// 16 blocks x 1024 threads; block owns 32 columns; thread = (16-row segment sg, col c).
__global__ __launch_bounds__(1024) void k_dt_colfin(
    const float* __restrict__ dist, const int* __restrict__ lab2,
    const float* __restrict__ img, Scal* __restrict__ s,
    float* __restrict__ out) {
  __shared__ float laf[32][32], lbb[32][32];
  __shared__ float smin[16], ssum[16];
  int t = threadIdx.x;
  int sg = t >> 5, c = t & 31;
  int j = blockIdx.x * 32 + c;
  int i0 = sg * 16;
  float rr[16];
  float fa = INF30, fb = INF30;
  #pragma unroll
  for (int il = 0; il < 16; ++il) {
    rr[il] = dist[(i0 + il) * W + j];
    float fi = (float)(i0 + il);
    fa = fminf(fa, rr[il] - fi);
    fb = fminf(fb, rr[il] + fi);
  }
  laf[sg][c] = fa;
  lbb[sg][c] = fb;
  __syncthreads();
  float cf = INF30, cb = INF30;
  #pragma unroll
  for (int bb = 0; bb < 32; ++bb) {
    if (bb < sg) cf = fminf(cf, laf[bb][c]);
    if (bb > sg) cb = fminf(cb, lbb[bb][c]);
  }
  int slv = s->sl;
  int p0 = s->p0;
  float ff[16];
  float m = cf;
  #pragma unroll
  for (int il = 0; il < 16; ++il) {
    float fi = (float)(i0 + il);
    m = fminf(m, rr[il] - fi);
    ff[il] = fi + m;
  }
  m = cb;
  float dv = BIG_F, cv = 0.0f;
  #pragma unroll
  for (int il = 15; il >= 0; --il) {           // final dist consumed in-register
    int pix = (i0 + il) * W + j;
    float fi = (float)(i0 + il);
    m = fminf(m, rr[il] + fi);
    float o = fminf(ff[il], m - fi);
    if (lab2[pix] == slv) { dv = fminf(dv, o); cv += img[pix]; }
    if (pix == p0) dv = fminf(dv, o);          // dist[p0] term, mask-independent
  }
  for (int off = 32; off; off >>= 1) {
    dv = fminf(dv, __shfl_down(dv, off, 64));
    cv += __shfl_down(cv, off, 64);
  }
  if ((t & 63) == 0) { smin[t >> 6] = dv; ssum[t >> 6] = cv; }
  __syncthreads();
  if (t == 0) {
    float mm = INF30, su = 0.0f;
    #pragma unroll
    for (int w = 0; w < 16; ++w) { mm = fminf(mm, smin[w]); su += ssum[w]; }
    atomicMin(&s->min_bits, __float_as_uint(mm));  // dist >= 0: uint order == float order
    atomicAdd(&s->cluster, su);
    __threadfence();
    unsigned old = atomicAdd(&s->done, 1u);
    if (old == gridDim.x - 1) {
      float fallback = (2.0f - (s->r0 + s->r1)) * 100.0f;
      out[0] = fallback;
      float min_d = __uint_as_float(atomicOr(&s->min_bits, 0u));
      float cl = atomicAdd(&s->cluster, 0.0f);
      float soa = s->soa;
      out[1] = s->both ? (min_d * soa * 10.0f * soa) : fallback;
      out[2] = s->both ? (cl * 90.0f) : fallback;
    }
  }
}

extern "C" void kernel_launch(void* const* d_in, const int* in_sizes, int n_in,
                              void* d_out, int out_size, void* d_ws, size_t ws_size,
                              hipStream_t stream) {
  const float* img = (const float*)d_in[0] + 3 * NPIX;   // result_given[3,0]
  const int* pts = (const int*)d_in[1] + 3 * 4;          // points_given[3]
  float* out = (float*)d_out;

  int* lab = (int*)d_ws;
  float* dist = (float*)d_ws + NPIX;
  char* base = (char*)d_ws + (size_t)2 * NPIX * 4;
  Scal* s = (Scal*)base;
  float* Asoa = (float*)(base + 64);
  int* lab2 = (int*)(base + 64 + 1024);

  k_local<<<256, 256, 0, stream>>>(img, lab, Asoa);
  k_border<<<61, 256, 0, stream>>>(lab, Asoa, s);
  k_dt_rows<<<H / 4, 256, 0, stream>>>(lab, lab2, img, pts, s, dist);
  k_dt_colfin<<<16, 1024, 0, stream>>>(dist, lab2, img, s, out);
}

// Round 9
// 99.798 us; speedup vs baseline: 2.2100x; 1.0217x over previous
//
#include <hip/hip_runtime.h>

#define H 512
#define W 512
#define NPIX (H * W)
#define BIG_I 1073741824   // 2^30
#define BIG_F 1.0e6f
#define INF30 1.0e30f

// ---- workspace layout ----
// [0, NPIX) int32       : lab  (union-find forest)
// [NPIX, 2*NPIX) float  : dist (row-pass result)
// then (64B aligned): Scal, Asoa[256], then lab2[NPIX] (final labels)
struct Scal {
  float soa;
  unsigned int min_bits;
  float cluster;
  unsigned int done;
  int both;
  float r0, r1;
  int sl, p0;
};

// ================= union-find (min-index roots) =================
__device__ __forceinline__ int rep(int* lab, int v) {
  int cur = lab[v];
  if (cur == v) return v;
  int prev = v, next;
  while (cur > (next = lab[cur])) { lab[prev] = next; prev = cur; cur = next; }
  return cur;
}
__device__ __forceinline__ void unite(int* lab, int a, int b) {
  int ra = rep(lab, a), rb = rep(lab, b);
  while (ra != rb) {
    if (ra < rb) { int t = ra; ra = rb; rb = t; }
    int old = atomicCAS(&lab[ra], ra, rb);
    if (old == ra) break;
    ra = rep(lab, old);
    rb = rep(lab, rb);
  }
}
// path-halving walk: writes only ancestors (monotone), safe concurrent w/ readers
__device__ __forceinline__ int root_ph(int* lab, int v) {
  int p = lab[v];
  if (p == v) return v;
  int gp = lab[p];
  while (p != gp) {
    lab[v] = gp;     // benign race: gp is an ancestor of v
    v = p; p = gp; gp = lab[p];
  }
  return p;
}
// run start column of bit c in mask (bit c must be set)
__device__ __forceinline__ int runstart(unsigned m, int c) {
  unsigned z = ~m & ((1u << c) - 1u);
  return z ? (32 - __clz((int)z)) : 0;
}

// ---- 1: per-tile (32x32) LDS CCL (run-based, pruned unions) + soa partial ----
__global__ __launch_bounds__(256) void k_local(const float* __restrict__ img,
                                               int* __restrict__ lab,
                                               float* __restrict__ Asoa) {
  __shared__ int sl[1024];           // only run-start slots are ever used
  __shared__ unsigned rmask[32];
  __shared__ float red[4];
  const int t = threadIdx.x, b = blockIdx.x;
  const int tileX = (b & 15) * 32;
  const int tileY = (b >> 4) * 32;
  const int r = t >> 3, c0 = (t & 7) * 4;     // thread owns 4 px of tile-row r
  const float4 x4 = *(const float4*)(img + (tileY + r) * W + tileX + c0);
  float acc = 4.0f - (x4.x + x4.y + x4.z + x4.w);
  unsigned nib = (rintf(x4.x) > 0.5f ? 1u : 0u) | (rintf(x4.y) > 0.5f ? 2u : 0u)
               | (rintf(x4.z) > 0.5f ? 4u : 0u) | (rintf(x4.w) > 0.5f ? 8u : 0u);
  unsigned m = nib << c0;                      // full row mask via OR over lanes 8r..8r+7
  m |= __shfl_xor(m, 1, 64);
  m |= __shfl_xor(m, 2, 64);
  m |= __shfl_xor(m, 4, 64);
  if ((t & 7) == 0) rmask[r] = m;
  unsigned startM = m & ~(m << 1);
  #pragma unroll
  for (int k = 0; k < 4; ++k) {                // init union-find at run starts only
    int c = c0 + k;
    if ((startM >> c) & 1u) sl[(r << 5) + c] = (r << 5) + c;
  }
  __syncthreads();
  if (r > 0) {
    unsigned ma = rmask[r - 1];
    unsigned upM = m & ma & (~(m << 1) | ~(ma << 1));      // one unite per (run, above-run) pair
    unsigned dL  = startM & (ma << 1) & ~ma;
    unsigned dR  = (m & ~(m >> 1)) & (ma >> 1) & ~ma;
    #pragma unroll
    for (int k = 0; k < 4; ++k) {
      int c = c0 + k;
      int myS = (r << 5) + runstart(m, c);
      if ((upM >> c) & 1u) unite(sl, myS, ((r - 1) << 5) + runstart(ma, c));
      if ((dL  >> c) & 1u) unite(sl, myS, ((r - 1) << 5) + runstart(ma, c - 1));
      if ((dR  >> c) & 1u) unite(sl, myS, ((r - 1) << 5) + c + 1);
    }
  }
  __syncthreads();
  int o[4];
  #pragma unroll
  for (int k = 0; k < 4; ++k) {
    int c = c0 + k;
    if ((m >> c) & 1u) {
      int rt = rep(sl, (r << 5) + runstart(m, c));
      o[k] = (tileY + (rt >> 5)) * W + tileX + (rt & 31);
    } else o[k] = BIG_I;
  }
  *(int4*)(lab + (tileY + r) * W + tileX + c0) = make_int4(o[0], o[1], o[2], o[3]);
  for (int off = 32; off; off >>= 1) acc += __shfl_down(acc, off, 64);
  if ((t & 63) == 0) red[t >> 6] = acc;
  __syncthreads();
  if (t == 0) Asoa[b] = red[0] + red[1] + red[2] + red[3];
}

// ---- 2: border merge (blocks 0..59) + soa reduce / Scal init (block 60) ----
__global__ void k_border(int* __restrict__ lab, const float* __restrict__ Asoa,
                         Scal* __restrict__ s) {
  int t = threadIdx.x;
  int gid = blockIdx.x * 256 + t;
  if (gid < 7680) {                            // horizontal boundary rows i=32,64,...
    int bb = gid >> 9, j = gid & 511;
    int i = (bb + 1) * 32;
    int p = i * W + j, q = p - W;
    if (lab[p] != BIG_I) {
      if (j > 0   && lab[q - 1] != BIG_I) unite(lab, p, q - 1);
      if (           lab[q]     != BIG_I) unite(lab, p, q);
      if (j < 511 && lab[q + 1] != BIG_I) unite(lab, p, q + 1);
    }
  } else if (gid < 15360) {                    // vertical boundary cols j=32,64,...
    int t2 = gid - 7680;
    int bb = t2 >> 9, i = t2 & 511;
    int j = (bb + 1) * 32;
    int p = i * W + j;
    int lp = lab[p], ll = lab[p - 1];
    if (lp != BIG_I && ll != BIG_I) unite(lab, p, p - 1);
    if (i & 31) {                              // diagonals not covered by horiz pass
      if (lp != BIG_I && lab[p - W - 1] != BIG_I) unite(lab, p, p - W - 1);
      if (ll != BIG_I && lab[p - W]     != BIG_I) unite(lab, p - 1, p - W);
    }
  } else if (t < 64) {                         // block 60: reduce soa partials + init
    float a = Asoa[t] + Asoa[t + 64] + Asoa[t + 128] + Asoa[t + 192];
    for (int off = 32; off; off >>= 1) a += __shfl_down(a, off, 64);
    if (t == 0) {
      s->soa = a;
      s->min_bits = __float_as_uint(BIG_F);
      s->cluster = 0.0f;
      s->done = 0u;
    }
  }
}

// ---- 3: flatten + row min-plus scan + cluster partial + scalar init ----
// 256 blocks x 128 threads; one wave per row.
__global__ __launch_bounds__(128) void k_dt_rows(int* __restrict__ lab,
                                                 int* __restrict__ lab2,
                                                 const float* __restrict__ img,
                                                 const int* __restrict__ pts,
                                                 Scal* __restrict__ s,
                                                 float* __restrict__ dist) {
  int lane = threadIdx.x & 63;
  int row = blockIdx.x * 2 + (threadIdx.x >> 6);
  int el = -1, sl2 = -1;
  if (lane == 0) {
    int p0 = pts[0] * W + pts[1], p1 = pts[2] * W + pts[3];
    int l0 = lab[p0], l1 = lab[p1];
    int both = (l0 != BIG_I) && (l1 != BIG_I);
    el = both ? root_ph(lab, l1) : -1;
    sl2 = both ? root_ph(lab, l0) : -1;
    if (blockIdx.x == 0 && threadIdx.x == 0) {
      s->both = both;
      s->sl = sl2;
      s->p0 = p0;
      s->r0 = img[p0];
      s->r1 = img[p1];
    }
  }
  el = __shfl(el, 0, 64);
  sl2 = __shfl(sl2, 0, 64);
  const int4* lp = (const int4*)(lab + row * W) + lane * 2;
  int4 a = lp[0], bq = lp[1];
  int v[8] = {a.x, a.y, a.z, a.w, bq.x, bq.y, bq.z, bq.w};
  int psrc = -1, proot = -1;
  #pragma unroll
  for (int k = 0; k < 8; ++k) {                // flatten w/ memo + halving
    if (v[k] == BIG_I) continue;
    if (v[k] == psrc) { v[k] = proot; continue; }
    psrc = v[k];
    proot = root_ph(lab, v[k]);
    v[k] = proot;
  }
  int4* l2 = (int4*)(lab2 + row * W) + lane * 2;
  l2[0] = make_int4(v[0], v[1], v[2], v[3]);
  l2[1] = make_int4(v[4], v[5], v[6], v[7]);
  // cluster partial: sum img over start-component pixels of this row
  const float4* ip = (const float4*)(img + row * W) + lane * 2;
  float4 i0q = ip[0], i1q = ip[1];
  float cv = 0.0f;
  if (v[0] == sl2) cv += i0q.x;
  if (v[1] == sl2) cv += i0q.y;
  if (v[2] == sl2) cv += i0q.z;
  if (v[3] == sl2) cv += i0q.w;
  if (v[4] == sl2) cv += i1q.x;
  if (v[5] == sl2) cv += i1q.y;
  if (v[6] == sl2) cv += i1q.z;
  if (v[7] == sl2) cv += i1q.w;
  for (int off = 32; off; off >>= 1) cv += __shfl_down(cv, off, 64);
  if (lane == 0 && cv != 0.0f) atomicAdd(&s->cluster, cv);
  // row min-plus scan
  float d[8];
  #pragma unroll
  for (int k = 0; k < 8; ++k) d[k] = (v[k] == el) ? 0.0f : BIG_F;
  int j0 = lane * 8;
  float pf[8], sb[8];
  float m = INF30;
  #pragma unroll
  for (int k = 0; k < 8; ++k) { m = fminf(m, d[k] - (float)(j0 + k)); pf[k] = m; }
  float tf = m;
  m = INF30;
  #pragma unroll
  for (int k = 7; k >= 0; --k) { m = fminf(m, d[k] + (float)(j0 + k)); sb[k] = m; }
  float tb = m;
  float vv = tf;
  #pragma unroll
  for (int off = 1; off < 64; off <<= 1) {
    float u = __shfl_up(vv, off, 64);
    if (lane >= off) vv = fminf(vv, u);
  }
  float ef = __shfl_up(vv, 1, 64); if (lane == 0) ef = INF30;
  vv = tb;
  #pragma unroll
  for (int off = 1; off < 64; off <<= 1) {
    float u = __shfl_down(vv, off, 64);
    if (lane < 64 - off) vv = fminf(vv, u);
  }
  float eb = __shfl_down(vv, 1, 64); if (lane == 63) eb = INF30;
  float o[8];
  #pragma unroll
  for (int k = 0; k < 8; ++k) {
    float j = (float)(j0 + k);
    o[k] = fminf(j + fminf(ef, pf[k]), -j + fminf(eb, sb[k]));
  }
  float4* dp = (float4*)(dist + row * W) + lane * 2;
  dp[0] = make_float4(o[0], o[1], o[2], o[3]);
  dp[1] = make_float4(o[4], o[5], o[6], o[7]);
}

// ---- 4: column DT (two-level scan via LDS) + masked min + finalize ----
// 32 blocks x 512 threads; block owns 16 columns; thread = (32 segments x 16 rows).
__global__ __launch_bounds__(512) void k_dt_colfin(
    const float* __restrict__ dist, const int* __restrict__ lab2,
    Scal* __restrict__ s, float* __restrict__ out) {
  __shared__ float laf[32][16], lbb[32][16];
  __shared__ float smin[8];
  int t = threadIdx.x;
  int sg = t >> 4, c = t & 15;
  int j = blockIdx.x * 16 + c;
  int i0 = sg * 16;
  float rr[16];
  float fa = INF30, fb = INF30;
  #pragma unroll
  for (int il = 0; il < 16; ++il) {
    rr[il] = dist[(i0 + il) * W + j];
    float fi = (float)(i0 + il);
    fa = fminf(fa, rr[il] - fi);
    fb = fminf(fb, rr[il] + fi);
  }
  laf[sg][c] = fa;
  lbb[sg][c] = fb;
  __syncthreads();
  float cf = INF30, cb = INF30;
  #pragma unroll
  for (int bb = 0; bb < 32; ++bb) {
    if (bb < sg) cf = fminf(cf, laf[bb][c]);
    if (bb > sg) cb = fminf(cb, lbb[bb][c]);
  }
  int slv = s->sl;
  int p0 = s->p0;
  float ff[16];
  float m = cf;
  #pragma unroll
  for (int il = 0; il < 16; ++il) {
    float fi = (float)(i0 + il);
    m = fminf(m, rr[il] - fi);
    ff[il] = fi + m;
  }
  m = cb;
  float dv = BIG_F;
  #pragma unroll
  for (int il = 15; il >= 0; --il) {           // final dist consumed in-register
    int pix = (i0 + il) * W + j;
    float fi = (float)(i0 + il);
    m = fminf(m, rr[il] + fi);
    float o = fminf(ff[il], m - fi);
    if (lab2[pix] == slv) dv = fminf(dv, o);
    if (pix == p0) dv = fminf(dv, o);          // dist[p0] term, mask-independent
  }
  for (int off = 32; off; off >>= 1)
    dv = fminf(dv, __shfl_down(dv, off, 64));
  if ((t & 63) == 0) smin[t >> 6] = dv;
  __syncthreads();
  if (t == 0) {
    float mm = INF30;
    #pragma unroll
    for (int w = 0; w < 8; ++w) mm = fminf(mm, smin[w]);
    atomicMin(&s->min_bits, __float_as_uint(mm));  // dist >= 0: uint order == float order
    __threadfence();
    unsigned old = atomicAdd(&s->done, 1u);
    if (old == gridDim.x - 1) {
      float fallback = (2.0f - (s->r0 + s->r1)) * 100.0f;
      out[0] = fallback;
      float min_d = __uint_as_float(atomicOr(&s->min_bits, 0u));
      float cl = atomicAdd(&s->cluster, 0.0f);
      float soa = s->soa;
      out[1] = s->both ? (min_d * soa * 10.0f * soa) : fallback;
      out[2] = s->both ? (cl * 90.0f) : fallback;
    }
  }
}

extern "C" void kernel_launch(void* const* d_in, const int* in_sizes, int n_in,
                              void* d_out, int out_size, void* d_ws, size_t ws_size,
                              hipStream_t stream) {
  const float* img = (const float*)d_in[0] + 3 * NPIX;   // result_given[3,0]
  const int* pts = (const int*)d_in[1] + 3 * 4;          // points_given[3]
  float* out = (float*)d_out;

  int* lab = (int*)d_ws;
  float* dist = (float*)d_ws + NPIX;
  char* base = (char*)d_ws + (size_t)2 * NPIX * 4;
  Scal* s = (Scal*)base;
  float* Asoa = (float*)(base + 64);
  int* lab2 = (int*)(base + 64 + 1024);

  k_local<<<256, 256, 0, stream>>>(img, lab, Asoa);
  k_border<<<61, 256, 0, stream>>>(lab, Asoa, s);
  k_dt_rows<<<H / 2, 128, 0, stream>>>(lab, lab2, img, pts, s, dist);
  k_dt_colfin<<<32, 512, 0, stream>>>(dist, lab2, s, out);
}

// Round 10
// 98.599 us; speedup vs baseline: 2.2369x; 1.0122x over previous
//
#include <hip/hip_runtime.h>

#define H 512
#define W 512
#define NPIX (H * W)
#define BIG_I 1073741824   // 2^30
#define BIG_F 1.0e6f
#define INF30 1.0e30f

// ---- workspace layout ----
// [0, NPIX) int32       : lab  (union-find forest)
// [NPIX, 2*NPIX) float  : dist (row-pass result)
// then (64B aligned): Scal, Asoa[256], then lab2[NPIX] (final labels)
struct Scal {
  float soa;
  unsigned int min_bits;
  float cluster;
  unsigned int done;
  int both;
  float r0, r1;
  int sl, p0;
};

// ================= union-find (min-index roots) =================
__device__ __forceinline__ int rep(int* lab, int v) {
  int cur = lab[v];
  if (cur == v) return v;
  int prev = v, next;
  while (cur > (next = lab[cur])) { lab[prev] = next; prev = cur; cur = next; }
  return cur;
}
__device__ __forceinline__ void unite(int* lab, int a, int b) {
  int ra = rep(lab, a), rb = rep(lab, b);
  while (ra != rb) {
    if (ra < rb) { int t = ra; ra = rb; rb = t; }
    int old = atomicCAS(&lab[ra], ra, rb);
    if (old == ra) break;
    ra = rep(lab, old);
    rb = rep(lab, rb);
  }
}
// path-halving walk: writes only ancestors (monotone), safe concurrent w/ readers
__device__ __forceinline__ int root_ph(int* lab, int v) {
  int p = lab[v];
  if (p == v) return v;
  int gp = lab[p];
  while (p != gp) {
    lab[v] = gp;     // benign race: gp is an ancestor of v
    v = p; p = gp; gp = lab[p];
  }
  return p;
}
// run start column of bit c in mask (bit c must be set)
__device__ __forceinline__ int runstart(unsigned m, int c) {
  unsigned z = ~m & ((1u << c) - 1u);
  return z ? (32 - __clz((int)z)) : 0;
}

// ---- 1: per-tile (32x32) LDS CCL (run-based, pruned unions) + soa partial ----
__global__ __launch_bounds__(256) void k_local(const float* __restrict__ img,
                                               int* __restrict__ lab,
                                               float* __restrict__ Asoa) {
  __shared__ int sl[1024];           // only run-start slots are ever used
  __shared__ unsigned rmask[32];
  __shared__ float red[4];
  const int t = threadIdx.x, b = blockIdx.x;
  const int tileX = (b & 15) * 32;
  const int tileY = (b >> 4) * 32;
  const int r = t >> 3, c0 = (t & 7) * 4;     // thread owns 4 px of tile-row r
  const float4 x4 = *(const float4*)(img + (tileY + r) * W + tileX + c0);
  float acc = 4.0f - (x4.x + x4.y + x4.z + x4.w);
  unsigned nib = (rintf(x4.x) > 0.5f ? 1u : 0u) | (rintf(x4.y) > 0.5f ? 2u : 0u)
               | (rintf(x4.z) > 0.5f ? 4u : 0u) | (rintf(x4.w) > 0.5f ? 8u : 0u);
  unsigned m = nib << c0;                      // full row mask via OR over lanes 8r..8r+7
  m |= __shfl_xor(m, 1, 64);
  m |= __shfl_xor(m, 2, 64);
  m |= __shfl_xor(m, 4, 64);
  if ((t & 7) == 0) rmask[r] = m;
  unsigned startM = m & ~(m << 1);
  #pragma unroll
  for (int k = 0; k < 4; ++k) {                // init union-find at run starts only
    int c = c0 + k;
    if ((startM >> c) & 1u) sl[(r << 5) + c] = (r << 5) + c;
  }
  __syncthreads();
  if (r > 0) {
    unsigned ma = rmask[r - 1];
    unsigned upM = m & ma & (~(m << 1) | ~(ma << 1));      // one unite per (run, above-run) pair
    unsigned dL  = startM & (ma << 1) & ~ma;
    unsigned dR  = (m & ~(m >> 1)) & (ma >> 1) & ~ma;
    #pragma unroll
    for (int k = 0; k < 4; ++k) {
      int c = c0 + k;
      int myS = (r << 5) + runstart(m, c);
      if ((upM >> c) & 1u) unite(sl, myS, ((r - 1) << 5) + runstart(ma, c));
      if ((dL  >> c) & 1u) unite(sl, myS, ((r - 1) << 5) + runstart(ma, c - 1));
      if ((dR  >> c) & 1u) unite(sl, myS, ((r - 1) << 5) + c + 1);
    }
  }
  __syncthreads();
  int o[4];
  #pragma unroll
  for (int k = 0; k < 4; ++k) {
    int c = c0 + k;
    if ((m >> c) & 1u) {
      int rt = rep(sl, (r << 5) + runstart(m, c));
      o[k] = (tileY + (rt >> 5)) * W + tileX + (rt & 31);
    } else o[k] = BIG_I;
  }
  *(int4*)(lab + (tileY + r) * W + tileX + c0) = make_int4(o[0], o[1], o[2], o[3]);
  for (int off = 32; off; off >>= 1) acc += __shfl_down(acc, off, 64);
  if ((t & 63) == 0) red[t >> 6] = acc;
  __syncthreads();
  if (t == 0) Asoa[b] = red[0] + red[1] + red[2] + red[3];
}

// ---- 2: border merge (run-deduped) + soa reduce / Scal init (block 60) ----
// Dedupe rule: skip a unite iff its (label,label) pair is identical to the
// immediately-preceding candidate in the boundary enumeration (the first of
// each run of identical pairs is always issued -> coverage preserved; unions
// are commutative/idempotent so cross-wave order is irrelevant).
__global__ void k_border(int* __restrict__ lab, const float* __restrict__ Asoa,
                         Scal* __restrict__ s) {
  int t = threadIdx.x;
  int lane = t & 63;
  int gid = blockIdx.x * 256 + t;
  if (gid < 7680) {                            // horizontal boundary rows i=32,64,...
    int bb = gid >> 9, j = gid & 511;
    int i = (bb + 1) * 32;
    int p = i * W + j, q = p - W;
    int a  = lab[p];                           // raw labels (tile roots)
    int u0 = lab[q];
    int um = (j > 0)   ? lab[q - 1] : BIG_I;
    int up = (j < 511) ? lab[q + 1] : BIG_I;
    int a_prev = __shfl_up(a, 1, 64);
    if (lane == 0) a_prev = (j > 0) ? lab[p - 1] : BIG_I;
    if (a != BIG_I) {
      // E_m: covered by left pixel's E_0 when same lower run
      if (um != BIG_I && a != a_prev) unite(lab, a, um);
      // E_0: identical to own E_m when upper label unchanged
      if (u0 != BIG_I && u0 != um) unite(lab, a, u0);
      // E_p: identical to own E_0 (or E_m when u0 is bg)
      if (up != BIG_I && up != u0 && !(u0 == BIG_I && up == um)) unite(lab, a, up);
    }
  } else if (gid < 15360) {                    // vertical boundary cols j=32,64,...
    int t2 = gid - 7680;
    int bb = t2 >> 9, i = t2 & 511;
    int j = (bb + 1) * 32;
    int p = i * W + j;
    int lp = lab[p], ll = lab[p - 1];
    int lpp = __shfl_up(lp, 1, 64);            // row i-1: lab[p-W]
    int llp = __shfl_up(ll, 1, 64);            // row i-1: lab[p-W-1]
    if (lane == 0) {
      lpp = (i > 0) ? lab[p - W] : BIG_I;
      llp = (i > 0) ? lab[p - W - 1] : BIG_I;
    }
    bool fgp = lp != BIG_I, fgl = ll != BIG_I;
    // V edge: covered by row i-1's V when both labels unchanged
    if (fgp && fgl && !(lp == lpp && ll == llp)) unite(lab, lp, ll);
    if ((i & 31) && i > 0) {                   // diagonals (i%32==0 covered by horiz pass)
      // d1 = (lp, lab[p-W-1]) ; covered by V(i-1) when lp==lpp
      if (fgp && llp != BIG_I && lp != lpp) unite(lab, lp, llp);
      // d2 = (ll, lab[p-W])   ; covered by V(i-1) when ll==llp
      if (fgl && lpp != BIG_I && ll != llp) unite(lab, ll, lpp);
    }
  } else if (t < 64) {                         // block 60: reduce soa partials + init
    float a = Asoa[t] + Asoa[t + 64] + Asoa[t + 128] + Asoa[t + 192];
    for (int off = 32; off; off >>= 1) a += __shfl_down(a, off, 64);
    if (t == 0) {
      s->soa = a;
      s->min_bits = __float_as_uint(BIG_F);
      s->cluster = 0.0f;
      s->done = 0u;
    }
  }
}

// ---- 3: flatten + row min-plus scan + cluster partial + scalar init ----
// 256 blocks x 128 threads; one wave per row.
__global__ __launch_bounds__(128) void k_dt_rows(int* __restrict__ lab,
                                                 int* __restrict__ lab2,
                                                 const float* __restrict__ img,
                                                 const int* __restrict__ pts,
                                                 Scal* __restrict__ s,
                                                 float* __restrict__ dist) {
  int lane = threadIdx.x & 63;
  int row = blockIdx.x * 2 + (threadIdx.x >> 6);
  int el = -1, sl2 = -1;
  if (lane == 0) {
    int p0 = pts[0] * W + pts[1], p1 = pts[2] * W + pts[3];
    int l0 = lab[p0], l1 = lab[p1];
    int both = (l0 != BIG_I) && (l1 != BIG_I);
    el = both ? root_ph(lab, l1) : -1;
    sl2 = both ? root_ph(lab, l0) : -1;
    if (blockIdx.x == 0 && threadIdx.x == 0) {
      s->both = both;
      s->sl = sl2;
      s->p0 = p0;
      s->r0 = img[p0];
      s->r1 = img[p1];
    }
  }
  el = __shfl(el, 0, 64);
  sl2 = __shfl(sl2, 0, 64);
  const int4* lp = (const int4*)(lab + row * W) + lane * 2;
  int4 a = lp[0], bq = lp[1];
  int v[8] = {a.x, a.y, a.z, a.w, bq.x, bq.y, bq.z, bq.w};
  int psrc = -1, proot = -1;
  #pragma unroll
  for (int k = 0; k < 8; ++k) {                // flatten w/ memo + halving
    if (v[k] == BIG_I) continue;
    if (v[k] == psrc) { v[k] = proot; continue; }
    psrc = v[k];
    proot = root_ph(lab, v[k]);
    v[k] = proot;
  }
  int4* l2 = (int4*)(lab2 + row * W) + lane * 2;
  l2[0] = make_int4(v[0], v[1], v[2], v[3]);
  l2[1] = make_int4(v[4], v[5], v[6], v[7]);
  // cluster partial: sum img over start-component pixels of this row
  const float4* ip = (const float4*)(img + row * W) + lane * 2;
  float4 i0q = ip[0], i1q = ip[1];
  float cv = 0.0f;
  if (v[0] == sl2) cv += i0q.x;
  if (v[1] == sl2) cv += i0q.y;
  if (v[2] == sl2) cv += i0q.z;
  if (v[3] == sl2) cv += i0q.w;
  if (v[4] == sl2) cv += i1q.x;
  if (v[5] == sl2) cv += i1q.y;
  if (v[6] == sl2) cv += i1q.z;
  if (v[7] == sl2) cv += i1q.w;
  for (int off = 32; off; off >>= 1) cv += __shfl_down(cv, off, 64);
  if (lane == 0 && cv != 0.0f) atomicAdd(&s->cluster, cv);
  // row min-plus scan
  float d[8];
  #pragma unroll
  for (int k = 0; k < 8; ++k) d[k] = (v[k] == el) ? 0.0f : BIG_F;
  int j0 = lane * 8;
  float pf[8], sb[8];
  float m = INF30;
  #pragma unroll
  for (int k = 0; k < 8; ++k) { m = fminf(m, d[k] - (float)(j0 + k)); pf[k] = m; }
  float tf = m;
  m = INF30;
  #pragma unroll
  for (int k = 7; k >= 0; --k) { m = fminf(m, d[k] + (float)(j0 + k)); sb[k] = m; }
  float tb = m;
  float vv = tf;
  #pragma unroll
  for (int off = 1; off < 64; off <<= 1) {
    float u = __shfl_up(vv, off, 64);
    if (lane >= off) vv = fminf(vv, u);
  }
  float ef = __shfl_up(vv, 1, 64); if (lane == 0) ef = INF30;
  vv = tb;
  #pragma unroll
  for (int off = 1; off < 64; off <<= 1) {
    float u = __shfl_down(vv, off, 64);
    if (lane < 64 - off) vv = fminf(vv, u);
  }
  float eb = __shfl_down(vv, 1, 64); if (lane == 63) eb = INF30;
  float o[8];
  #pragma unroll
  for (int k = 0; k < 8; ++k) {
    float j = (float)(j0 + k);
    o[k] = fminf(j + fminf(ef, pf[k]), -j + fminf(eb, sb[k]));
  }
  float4* dp = (float4*)(dist + row * W) + lane * 2;
  dp[0] = make_float4(o[0], o[1], o[2], o[3]);
  dp[1] = make_float4(o[4], o[5], o[6], o[7]);
}

// ---- 4: column DT (two-level scan via LDS) + masked min + finalize ----
// 32 blocks x 512 threads; block owns 16 columns; thread = (32 segments x 16 rows).
__global__ __launch_bounds__(512) void k_dt_colfin(
    const float* __restrict__ dist, const int* __restrict__ lab2,
    Scal* __restrict__ s, float* __restrict__ out) {
  __shared__ float laf[32][16], lbb[32][16];
  __shared__ float smin[8];
  int t = threadIdx.x;
  int sg = t >> 4, c = t & 15;
  int j = blockIdx.x * 16 + c;
  int i0 = sg * 16;
  float rr[16];
  float fa = INF30, fb = INF30;
  #pragma unroll
  for (int il = 0; il < 16; ++il) {
    rr[il] = dist[(i0 + il) * W + j];
    float fi = (float)(i0 + il);
    fa = fminf(fa, rr[il] - fi);
    fb = fminf(fb, rr[il] + fi);
  }
  laf[sg][c] = fa;
  lbb[sg][c] = fb;
  __syncthreads();
  float cf = INF30, cb = INF30;
  #pragma unroll
  for (int bb = 0; bb < 32; ++bb) {
    if (bb < sg) cf = fminf(cf, laf[bb][c]);
    if (bb > sg) cb = fminf(cb, lbb[bb][c]);
  }
  int slv = s->sl;
  int p0 = s->p0;
  float ff[16];
  float m = cf;
  #pragma unroll
  for (int il = 0; il < 16; ++il) {
    float fi = (float)(i0 + il);
    m = fminf(m, rr[il] - fi);
    ff[il] = fi + m;
  }
  m = cb;
  float dv = BIG_F;
  #pragma unroll
  for (int il = 15; il >= 0; --il) {           // final dist consumed in-register
    int pix = (i0 + il) * W + j;
    float fi = (float)(i0 + il);
    m = fminf(m, rr[il] + fi);
    float o = fminf(ff[il], m - fi);
    if (lab2[pix] == slv) dv = fminf(dv, o);
    if (pix == p0) dv = fminf(dv, o);          // dist[p0] term, mask-independent
  }
  for (int off = 32; off; off >>= 1)
    dv = fminf(dv, __shfl_down(dv, off, 64));
  if ((t & 63) == 0) smin[t >> 6] = dv;
  __syncthreads();
  if (t == 0) {
    float mm = INF30;
    #pragma unroll
    for (int w = 0; w < 8; ++w) mm = fminf(mm, smin[w]);
    atomicMin(&s->min_bits, __float_as_uint(mm));  // dist >= 0: uint order == float order
    __threadfence();
    unsigned old = atomicAdd(&s->done, 1u);
    if (old == gridDim.x - 1) {
      float fallback = (2.0f - (s->r0 + s->r1)) * 100.0f;
      out[0] = fallback;
      float min_d = __uint_as_float(atomicOr(&s->min_bits, 0u));
      float cl = atomicAdd(&s->cluster, 0.0f);
      float soa = s->soa;
      out[1] = s->both ? (min_d * soa * 10.0f * soa) : fallback;
      out[2] = s->both ? (cl * 90.0f) : fallback;
    }
  }
}

extern "C" void kernel_launch(void* const* d_in, const int* in_sizes, int n_in,
                              void* d_out, int out_size, void* d_ws, size_t ws_size,
                              hipStream_t stream) {
  const float* img = (const float*)d_in[0] + 3 * NPIX;   // result_given[3,0]
  const int* pts = (const int*)d_in[1] + 3 * 4;          // points_given[3]
  float* out = (float*)d_out;

  int* lab = (int*)d_ws;
  float* dist = (float*)d_ws + NPIX;
  char* base = (char*)d_ws + (size_t)2 * NPIX * 4;
  Scal* s = (Scal*)base;
  float* Asoa = (float*)(base + 64);
  int* lab2 = (int*)(base + 64 + 1024);

  k_local<<<256, 256, 0, stream>>>(img, lab, Asoa);
  k_border<<<61, 256, 0, stream>>>(lab, Asoa, s);
  k_dt_rows<<<H / 2, 128, 0, stream>>>(lab, lab2, img, pts, s, dist);
  k_dt_colfin<<<32, 512, 0, stream>>>(dist, lab2, s, out);
}